// Round 7
// baseline (24682.826 us; speedup 1.0000x reference)
//
#include <hip/hip_runtime.h>
#include <math.h>

#define Bn 64
#define Hn 1024
#define En 512
#define Sn 512
#define NB 64          // blocks in dataflow kernel; block owns 16 units x 4 gates

typedef _Float16 f16;
typedef _Float16 half8 __attribute__((ext_vector_type(8)));
typedef float f32x4 __attribute__((ext_vector_type(4)));

// ============================================================================
// Round 7: single persistent dataflow kernel. h passes between blocks as
// tagged words (tag<<16 | f16bits) via relaxed agent-scope atomics (sc0 sc1,
// LLC-coherent, NO fences -> L2-resident weights survive). Double-buffered by
// step parity; consumer at step t polls buffer t&1 for tag==t.
//
// Fragment layouts (gfx950 mfma_f32_16x16x32_f16, HW-verified):
//   A[m][k]: m = lane&15, k = (lane>>4)*8 + j
//   B[k][n]: n = lane&15, k = (lane>>4)*8 + j
//   C/D[m][n]: n = lane&15, m = (lane>>4)*4 + reg
//
// hT (tagged uint32, 2 bufs x 65536): word for h[b][u]:
//   kc=u>>5, f=kc*4+(b>>4), j=u&7, lane=(((u&31)>>3)<<4)|(b&15)
//   idx = (f*8+j)*64+lane   (transposed [frag][j][lane] -> coalesced polls)
// eF (A-side f16): [s][(kcx*4+mf)*64+lane]*8+j, e-k 0..511.
// wq (B-side f16, hi + lo*2048): [((blk*48+kc)*4+g)*64+lane]*8+j =
//   W_g[u=blk*16+(lane&15)][k]; kc<32: Wh_g @ k=kc*32+(lane>>4)*8+j;
//   kc>=32: Wx_g @ (kc-32)*32+(lane>>4)*8+j.
// ============================================================================

__global__ __launch_bounds__(256) void wqpack_kernel(
    const float* __restrict__ Whi_, const float* __restrict__ Whf_,
    const float* __restrict__ Whg_, const float* __restrict__ Who_,
    const float* __restrict__ Wxi_, const float* __restrict__ Wxf_,
    const float* __restrict__ Wxg_, const float* __restrict__ Wxo_,
    f16* __restrict__ wqHi, f16* __restrict__ wqLo)
{
    int t = blockIdx.x * 256 + threadIdx.x;   // 786432 = 64*48*4*64
    int lane = t & 63;
    int g = (t >> 6) & 3;
    int rest = t >> 8;
    int kc = rest % 48;
    int blk = rest / 48;
    int u = blk * 16 + (lane & 15);
    int klo = (lane >> 4) << 3;
    const float* Wh = (g == 0 ? Whi_ : g == 1 ? Whf_ : g == 2 ? Whg_ : Who_);
    const float* Wx = (g == 0 ? Wxi_ : g == 1 ? Wxf_ : g == 2 ? Wxg_ : Wxo_);
    const float* src = (kc < 32) ? (Wh + (size_t)u * Hn + kc * 32 + klo)
                                 : (Wx + (size_t)u * En + (kc - 32) * 32 + klo);
    float4 v0 = ((const float4*)src)[0];
    float4 v1 = ((const float4*)src)[1];
    float w[8] = {v0.x, v0.y, v0.z, v0.w, v1.x, v1.y, v1.z, v1.w};
    #pragma unroll
    for (int j = 0; j < 8; ++j) {
        f16 hi = (f16)w[j];
        float lo = (w[j] - (float)hi) * 2048.0f;
        wqHi[(size_t)t * 8 + j] = hi;
        wqLo[(size_t)t * 8 + j] = (f16)lo;
    }
}

__global__ __launch_bounds__(256) void epack_kernel(
    const int* __restrict__ x, const float* __restrict__ emb,
    f16* __restrict__ eF)
{
    int t = blockIdx.x * 256 + threadIdx.x;   // 2097152 = 512*16*4*64
    int lane = t & 63;
    int q = t >> 6;
    int mt = q & 3; q >>= 2;
    int kc2 = q & 15;
    int s = q >> 4;
    int b = mt * 16 + (lane & 15);
    int tok = x[b * Sn + s];
    int k = kc2 * 32 + ((lane >> 4) << 3);
    const float* src = emb + (size_t)tok * En + k;
    float4 v0 = ((const float4*)src)[0];
    float4 v1 = ((const float4*)src)[1];
    f16* dst = eF + (size_t)t * 8;
    dst[0] = (f16)v0.x; dst[1] = (f16)v0.y; dst[2] = (f16)v0.z; dst[3] = (f16)v0.w;
    dst[4] = (f16)v1.x; dst[5] = (f16)v1.y; dst[6] = (f16)v1.z; dst[7] = (f16)v1.w;
}

__device__ __forceinline__ bool tagsOk(const unsigned int* w, unsigned int want) {
    unsigned int d = 0;
    #pragma unroll
    for (int j = 0; j < 8; ++j) d |= (w[j] >> 16) ^ want;
    return d == 0;
}

__device__ __forceinline__ half8 buildA(const unsigned int* w) {
    half8 a;
    #pragma unroll
    for (int j = 0; j < 8; ++j)
        a[j] = __builtin_bit_cast(f16, (unsigned short)(w[j] & 0xFFFFu));
    return a;
}

#define HLOAD(dst, f)                                                        \
    _Pragma("unroll")                                                        \
    for (int j = 0; j < 8; ++j)                                              \
        dst[j] = __hip_atomic_load(hR + (((f) * 8 + j) << 6) + lane,         \
                                   __ATOMIC_RELAXED, __HIP_MEMORY_SCOPE_AGENT);

// ---- the whole sequence in one kernel, 64 blocks x 1024 threads ----
__global__ __launch_bounds__(1024) void lstm_seq(
    unsigned int* __restrict__ hT,        // 2 x 65536 tagged words
    const half8* __restrict__ eF,
    const half8* __restrict__ wqHi, const half8* __restrict__ wqLo,
    const float* __restrict__ bi, const float* __restrict__ bf,
    const float* __restrict__ bg, const float* __restrict__ bo,
    float* __restrict__ hFinal, float* __restrict__ cFinal)
{
    __shared__ float preW[4][4][4][16][16];   // [kq][mf][g][m][n] = 64 KB

    const int tid  = threadIdx.x;
    const int lane = tid & 63;
    const int wv   = tid >> 6;
    const int mf   = wv & 3;
    const int kq   = wv >> 2;
    const int blk  = blockIdx.x;

    // cell-thread identity (all 1024 threads are cell threads: 64 b x 16 u)
    const int bc = tid >> 4, uc = tid & 15;
    const int ucol = blk * 16 + uc;
    const float biR = bi[ucol], bfR = bf[ucol], bgR = bg[ucol], boR = bo[ucol];
    float cR = 0.0f;
    // producer tagged-store index
    const int pf = (ucol >> 5) * 4 + (bc >> 4);
    const int pIdx = (pf * 8 + (ucol & 7)) * 64
                   + ((((ucol & 31) >> 3) << 4) | (bc & 15));

    const half8* wqB = wqHi + (size_t)(blk * 48) * 4 * 64 + lane;
    const half8* wqL = wqLo + (size_t)(blk * 48) * 4 * 64 + lane;

    for (int t = 0; t < Sn; ++t) {
        unsigned int* hR = hT + (size_t)(t & 1) * 65536;
        const unsigned int want = (unsigned int)t;
        const half8* eFs = eF + (size_t)t * 4096 + lane;

        f32x4 accH[4], accL[4];
        #pragma unroll
        for (int g = 0; g < 4; ++g) {
            accH[g] = (f32x4){0.f, 0.f, 0.f, 0.f};
            accL[g] = (f32x4){0.f, 0.f, 0.f, 0.f};
        }

        unsigned int w0[4][8], w1[4][8];
        // issue h batch 0 (kc = kq+4i, i=0..3)
        #pragma unroll
        for (int i = 0; i < 4; ++i) { HLOAD(w0[i], (kq + 4 * i) * 4 + mf); }

        // e-part (independent of h -> hides h latency):
        // kcx = kq + 4*ie over ie 0..3
        #pragma unroll
        for (int ie = 0; ie < 4; ++ie) {
            int kcx = kq + 4 * ie;
            half8 a = eFs[(size_t)((kcx * 4 + mf) * 64)];
            #pragma unroll
            for (int g = 0; g < 4; ++g) {
                half8 bh = wqB[(size_t)((32 + kcx) * 4 + g) * 64];
                half8 bl = wqL[(size_t)((32 + kcx) * 4 + g) * 64];
                accH[g] = __builtin_amdgcn_mfma_f32_16x16x32_f16(a, bh, accH[g], 0, 0, 0);
                accL[g] = __builtin_amdgcn_mfma_f32_16x16x32_f16(a, bl, accL[g], 0, 0, 0);
            }
        }

        // issue h batch 1 (kc = kq+16+4i)
        #pragma unroll
        for (int i = 0; i < 4; ++i) { HLOAD(w1[i], (kq + 16 + 4 * i) * 4 + mf); }

        // consume batch 0
        #pragma unroll
        for (int i = 0; i < 4; ++i) {
            int kc = kq + 4 * i;
            while (!tagsOk(w0[i], want)) {
                __builtin_amdgcn_s_sleep(1);
                HLOAD(w0[i], kc * 4 + mf);
            }
            half8 a = buildA(w0[i]);
            #pragma unroll
            for (int g = 0; g < 4; ++g) {
                half8 bh = wqB[(size_t)(kc * 4 + g) * 64];
                half8 bl = wqL[(size_t)(kc * 4 + g) * 64];
                accH[g] = __builtin_amdgcn_mfma_f32_16x16x32_f16(a, bh, accH[g], 0, 0, 0);
                accL[g] = __builtin_amdgcn_mfma_f32_16x16x32_f16(a, bl, accL[g], 0, 0, 0);
            }
        }
        // consume batch 1
        #pragma unroll
        for (int i = 0; i < 4; ++i) {
            int kc = kq + 16 + 4 * i;
            while (!tagsOk(w1[i], want)) {
                __builtin_amdgcn_s_sleep(1);
                HLOAD(w1[i], kc * 4 + mf);
            }
            half8 a = buildA(w1[i]);
            #pragma unroll
            for (int g = 0; g < 4; ++g) {
                half8 bh = wqB[(size_t)(kc * 4 + g) * 64];
                half8 bl = wqL[(size_t)(kc * 4 + g) * 64];
                accH[g] = __builtin_amdgcn_mfma_f32_16x16x32_f16(a, bh, accH[g], 0, 0, 0);
                accL[g] = __builtin_amdgcn_mfma_f32_16x16x32_f16(a, bl, accL[g], 0, 0, 0);
            }
        }

        // fold hi/lo and exchange via LDS: D m=(lane>>4)*4+r, n=lane&15
        #pragma unroll
        for (int g = 0; g < 4; ++g) {
            #pragma unroll
            for (int r = 0; r < 4; ++r) {
                float v = accH[g][r] + accL[g][r] * (1.0f / 2048.0f);
                preW[kq][mf][g][((lane >> 4) << 2) + r][lane & 15] = v;
            }
        }
        __syncthreads();

        // cell update: thread = (bc, uc)
        {
            const int m4 = bc >> 4, msub = bc & 15;
            float s0 = preW[0][m4][0][msub][uc] + preW[1][m4][0][msub][uc]
                     + preW[2][m4][0][msub][uc] + preW[3][m4][0][msub][uc] + biR;
            float s1 = preW[0][m4][1][msub][uc] + preW[1][m4][1][msub][uc]
                     + preW[2][m4][1][msub][uc] + preW[3][m4][1][msub][uc] + bfR;
            float s2 = preW[0][m4][2][msub][uc] + preW[1][m4][2][msub][uc]
                     + preW[2][m4][2][msub][uc] + preW[3][m4][2][msub][uc] + bgR;
            float s3 = preW[0][m4][3][msub][uc] + preW[1][m4][3][msub][uc]
                     + preW[2][m4][3][msub][uc] + preW[3][m4][3][msub][uc] + boR;
            float it = 1.f / (1.f + expf(-s0));
            float ft = 1.f / (1.f + expf(-s1));
            float gt = tanhf(s2);
            float ot = 1.f / (1.f + expf(-s3));
            float cn = ft * cR + it * gt;
            cR = cn;
            float hn = ot * tanhf(cn);
            unsigned short hb = __builtin_bit_cast(unsigned short, (f16)hn);
            unsigned int word = ((unsigned int)(t + 1) << 16) | (unsigned int)hb;
            __hip_atomic_store(hT + (size_t)((t + 1) & 1) * 65536 + pIdx, word,
                               __ATOMIC_RELAXED, __HIP_MEMORY_SCOPE_AGENT);
            if (t == Sn - 1) {
                hFinal[bc * Hn + ucol] = hn;
                cFinal[bc * Hn + ucol] = cn;
            }
        }
        __syncthreads();   // protect preW before next step's writes
    }
}

// ---- tail ----
__global__ __launch_bounds__(256) void copy_hc(
    const float* __restrict__ h, const float* __restrict__ c,
    float* __restrict__ out)
{
    int i = blockIdx.x * 256 + threadIdx.x;
    out[128 + i] = h[i];
    out[128 + Bn * Hn + i] = c[i];
}

__global__ __launch_bounds__(64) void classifier(
    const float* __restrict__ h, const float* __restrict__ Vw,
    const float* __restrict__ Vb, float* __restrict__ out)
{
    int bid = blockIdx.x;
    int b = bid >> 1, n = bid & 1;
    int lane = threadIdx.x;
    float sum = 0.f;
    for (int k = lane; k < Hn; k += 64)
        sum += h[b * Hn + k] * Vw[n * Hn + k];
    #pragma unroll
    for (int off = 32; off > 0; off >>= 1)
        sum += __shfl_down(sum, off, 64);
    if (lane == 0)
        out[b * 2 + n] = sum + Vb[n];
}

// ======================= fallback (round-1 proven path) =======================

#define KT 128
#define KTP 132

__global__ __launch_bounds__(256) void lstm_step_fb(
    const int* __restrict__ x, const float* __restrict__ emb,
    const float* __restrict__ Wxi, const float* __restrict__ Wxf,
    const float* __restrict__ Wxg, const float* __restrict__ Wxo,
    const float* __restrict__ bi, const float* __restrict__ bf,
    const float* __restrict__ bg, const float* __restrict__ bo,
    const float* __restrict__ Whi, const float* __restrict__ Whf,
    const float* __restrict__ Whg, const float* __restrict__ Who,
    const float* __restrict__ h_in, const float* __restrict__ c_in,
    float* __restrict__ h_out, float* __restrict__ c_out, int s)
{
    __shared__ float sh[Bn][KTP];
    __shared__ float sw[16][KTP];
    const int tid = threadIdx.x;
    const int b = tid >> 2, j = tid & 3;
    const int cb = blockIdx.x * 4, col = cb + j;
    float acc0 = 0.f, acc1 = 0.f, acc2 = 0.f, acc3 = 0.f;

    for (int k0 = 0; k0 < En; k0 += KT) {
        for (int i = tid; i < Bn * (KT / 4); i += 256) {
            int bl = i >> 5, k4 = (i & 31) << 2;
            int tok = x[bl * Sn + s];
            *reinterpret_cast<float4*>(&sh[bl][k4]) =
                *reinterpret_cast<const float4*>(&emb[(size_t)tok * En + k0 + k4]);
        }
        for (int i = tid; i < 16 * (KT / 4); i += 256) {
            int r = i >> 5, k4 = (i & 31) << 2;
            const float* Wg = (r < 8) ? ((r < 4) ? Wxi : Wxf)
                                      : ((r < 12) ? Wxg : Wxo);
            *reinterpret_cast<float4*>(&sw[r][k4]) =
                *reinterpret_cast<const float4*>(&Wg[(size_t)(cb + (r & 3)) * En + k0 + k4]);
        }
        __syncthreads();
        #pragma unroll 8
        for (int k = 0; k < KT; k += 4) {
            float4 hv = *reinterpret_cast<const float4*>(&sh[b][k]);
            float4 w0 = *reinterpret_cast<const float4*>(&sw[j][k]);
            float4 w1 = *reinterpret_cast<const float4*>(&sw[4 + j][k]);
            float4 w2 = *reinterpret_cast<const float4*>(&sw[8 + j][k]);
            float4 w3 = *reinterpret_cast<const float4*>(&sw[12 + j][k]);
            acc0 += hv.x*w0.x + hv.y*w0.y + hv.z*w0.z + hv.w*w0.w;
            acc1 += hv.x*w1.x + hv.y*w1.y + hv.z*w1.z + hv.w*w1.w;
            acc2 += hv.x*w2.x + hv.y*w2.y + hv.z*w2.z + hv.w*w2.w;
            acc3 += hv.x*w3.x + hv.y*w3.y + hv.z*w3.z + hv.w*w3.w;
        }
        __syncthreads();
    }
    for (int k0 = 0; k0 < Hn; k0 += KT) {
        for (int i = tid; i < Bn * (KT / 4); i += 256) {
            int bl = i >> 5, k4 = (i & 31) << 2;
            *reinterpret_cast<float4*>(&sh[bl][k4]) =
                *reinterpret_cast<const float4*>(&h_in[(size_t)bl * Hn + k0 + k4]);
        }
        for (int i = tid; i < 16 * (KT / 4); i += 256) {
            int r = i >> 5, k4 = (i & 31) << 2;
            const float* Wg = (r < 8) ? ((r < 4) ? Whi : Whf)
                                      : ((r < 12) ? Whg : Who);
            *reinterpret_cast<float4*>(&sw[r][k4]) =
                *reinterpret_cast<const float4*>(&Wg[(size_t)(cb + (r & 3)) * Hn + k0 + k4]);
        }
        __syncthreads();
        #pragma unroll 8
        for (int k = 0; k < KT; k += 4) {
            float4 hv = *reinterpret_cast<const float4*>(&sh[b][k]);
            float4 w0 = *reinterpret_cast<const float4*>(&sw[j][k]);
            float4 w1 = *reinterpret_cast<const float4*>(&sw[4 + j][k]);
            float4 w2 = *reinterpret_cast<const float4*>(&sw[8 + j][k]);
            float4 w3 = *reinterpret_cast<const float4*>(&sw[12 + j][k]);
            acc0 += hv.x*w0.x + hv.y*w0.y + hv.z*w0.z + hv.w*w0.w;
            acc1 += hv.x*w1.x + hv.y*w1.y + hv.z*w1.z + hv.w*w1.w;
            acc2 += hv.x*w2.x + hv.y*w2.y + hv.z*w2.z + hv.w*w2.w;
            acc3 += hv.x*w3.x + hv.y*w3.y + hv.z*w3.z + hv.w*w3.w;
        }
        __syncthreads();
    }
    acc0 += bi[col]; acc1 += bf[col]; acc2 += bg[col]; acc3 += bo[col];
    float it = 1.f / (1.f + expf(-acc0));
    float ft = 1.f / (1.f + expf(-acc1));
    float gt = tanhf(acc2);
    float ot = 1.f / (1.f + expf(-acc3));
    float cn = ft * c_in[b * Hn + col] + it * gt;
    c_out[b * Hn + col] = cn;
    h_out[b * Hn + col] = ot * tanhf(cn);
}

// ======================= launcher =======================

extern "C" void kernel_launch(void* const* d_in, const int* in_sizes, int n_in,
                              void* d_out, int out_size, void* d_ws, size_t ws_size,
                              hipStream_t stream) {
    const int*   x   = (const int*)  d_in[0];
    const float* emb = (const float*)d_in[1];
    const float* Wxi = (const float*)d_in[2];
    const float* bi  = (const float*)d_in[3];
    const float* Whi = (const float*)d_in[4];
    const float* Wxf = (const float*)d_in[5];
    const float* bf  = (const float*)d_in[6];
    const float* Whf = (const float*)d_in[7];
    const float* Wxg = (const float*)d_in[8];
    const float* bg  = (const float*)d_in[9];
    const float* Whg = (const float*)d_in[10];
    const float* Wxo = (const float*)d_in[11];
    const float* bo  = (const float*)d_in[12];
    const float* Who = (const float*)d_in[13];
    const float* Vw  = (const float*)d_in[14];
    const float* Vb  = (const float*)d_in[15];
    float* out = (float*)d_out;

    // ws: [hT 512K][c 256K][h 256K][eF 32M][wqHi 12M][wqLo 12M] ~ 57 MB
    const size_t szHT = (size_t)2 * 65536 * sizeof(unsigned int);     // 512 KB
    const size_t szC  = (size_t)Bn * Hn * sizeof(float);              // 256 KB
    const size_t szEF = (size_t)Sn * 16 * 4 * 64 * 8 * sizeof(f16);   // 32 MB
    const size_t szWq = (size_t)NB * 48 * 4 * 64 * 8 * sizeof(f16);   // 12 MB
    const size_t need = szHT + 2 * szC + szEF + 2 * szWq;

    if (ws_size >= need) {
        char* base = (char*)d_ws;
        unsigned int* hT = (unsigned int*)base; base += szHT;
        float* c    = (float*)base; base += szC;
        float* h    = (float*)base; base += szC;
        f16*   eF   = (f16*)base;   base += szEF;
        f16*   wqHi = (f16*)base;   base += szWq;
        f16*   wqLo = (f16*)base;

        hipMemsetAsync(d_ws, 0, szHT, stream);   // h_0 = 0 with tag 0
        wqpack_kernel<<<dim3(3072), dim3(256), 0, stream>>>(
            Whi, Whf, Whg, Who, Wxi, Wxf, Wxg, Wxo, wqHi, wqLo);
        epack_kernel<<<dim3(8192), dim3(256), 0, stream>>>(x, emb, eF);

        lstm_seq<<<dim3(NB), dim3(1024), 0, stream>>>(
            hT, (const half8*)eF, (const half8*)wqHi, (const half8*)wqLo,
            bi, bf, bg, bo, h, c);

        copy_hc<<<dim3(Bn * Hn / 256), dim3(256), 0, stream>>>(h, c, out);
        classifier<<<dim3(Bn * 2), dim3(64), 0, stream>>>(h, Vw, Vb, out);
    } else {
        float* hA = (float*)d_ws;
        float* cA = hA + Bn * Hn;
        float* hB = cA + Bn * Hn;
        float* cB = hB + Bn * Hn;
        hipMemsetAsync(d_ws, 0, (size_t)2 * Bn * Hn * sizeof(float), stream);
        for (int s = 0; s < Sn; ++s) {
            const float* hi = (s & 1) ? hB : hA;
            const float* ci = (s & 1) ? cB : cA;
            float* ho = (s & 1) ? hA : hB;
            float* co = (s & 1) ? cA : cB;
            lstm_step_fb<<<dim3(Hn / 4), dim3(256), 0, stream>>>(
                x, emb, Wxi, Wxf, Wxg, Wxo, bi, bf, bg, bo,
                Whi, Whf, Whg, Who, hi, ci, ho, co, s);
        }
        copy_hc<<<dim3(Bn * Hn / 256), dim3(256), 0, stream>>>(hA, cA, out);
        classifier<<<dim3(Bn * 2), dim3(64), 0, stream>>>(hA, Vw, Vb, out);
    }
}